// Round 6
// baseline (199.300 us; speedup 1.0000x reference)
//
#include <hip/hip_runtime.h>

typedef __bf16 bf16;
typedef __bf16 bf16x8 __attribute__((ext_vector_type(8)));
typedef float  f32x4  __attribute__((ext_vector_type(4)));

// Problem constants
#define NSPEC   512          // 256 pairs * 2
#define BOUT    9999         // GROUPS*3
#define K0A     10240        // BOUT padded to 8*10*128 (ksplit*kiters*BK)
#define N00     1024         // 1000 padded
#define N01     896          // 800 padded
#define N02     896
#define N03     448          // 400 padded (14*32)

// async global->LDS, 16B per lane; lds base must be wave-uniform (HW adds lane*16)
__device__ __forceinline__ void gload_lds16(const bf16* g, bf16* l) {
    auto* gp = reinterpret_cast<const __attribute__((address_space(1))) unsigned int*>(
        reinterpret_cast<uintptr_t>(g));
    auto* lp = reinterpret_cast<__attribute__((address_space(3))) unsigned int*>(
        reinterpret_cast<uintptr_t>(l));
    __builtin_amdgcn_global_load_lds(gp, lp, 16, 0, 0);
}

// ---------------- transpose helper: 64(n) x 32(k) tile, 512 threads ----------------
// src (K x N) fp32 row-major -> dst (N0 x K0) bf16 (k-contiguous)
__device__ __forceinline__ void transpose_tile64(const float* __restrict__ src,
                                                 bf16* __restrict__ dst,
                                                 int K, int N, int K0,
                                                 float* tile, int bx, int by) {
    int n0 = bx * 64, k0 = by * 32;
    int t = threadIdx.x;
    {
        int kr = t >> 4, nc = (t & 15) * 4;          // 32 rows x 64 cols
        int gk = k0 + kr;
#pragma unroll
        for (int e = 0; e < 4; ++e) {
            int gn = n0 + nc + e;
            tile[kr * 65 + nc + e] = (gk < K && gn < N) ? src[(size_t)gk * N + gn] : 0.0f;
        }
    }
    __syncthreads();
    {
        int nr = t >> 3, kc = (t & 7) * 4;           // 64 n-rows x 32 k-cols
        bf16 v[4];
#pragma unroll
        for (int e = 0; e < 4; ++e) v[e] = (bf16)tile[(kc + e) * 65 + nr];
        *(ushort4*)&dst[(size_t)(n0 + nr) * K0 + k0 + kc] = *(ushort4*)v;
    }
}

// ---------------- mega-prep: weight transposes + build_A + zero psums ----------------
__global__ __launch_bounds__(512) void prep_all(const float* __restrict__ mz,
                                                const float* __restrict__ inten,
                                                const float* __restrict__ bw,
                                                const float* __restrict__ bb,
                                                const float* __restrict__ w0,
                                                const float* __restrict__ w1,
                                                const float* __restrict__ w2,
                                                const float* __restrict__ we,
                                                bf16* __restrict__ A,
                                                bf16* __restrict__ B0t,
                                                bf16* __restrict__ B1t,
                                                bf16* __restrict__ B2t,
                                                bf16* __restrict__ BEt,
                                                float* __restrict__ psums) {
    __shared__ float smem[K0A];    // 40 KB: sacc for build_A, tile[32*65] for transposes
    int b = blockIdx.x;
    if (b < 5120) {                       // w0 -> B0t: 16 n-tiles x 320 k-tiles
        transpose_tile64(w0, B0t, BOUT, 1000, K0A, smem, b & 15, b >> 4);
    } else if (b < 5568) {                // w1 -> B1t: 14 x 32
        int r = b - 5120;
        transpose_tile64(w1, B1t, 1000, 800, 1024, smem, r % 14, r / 14);
    } else if (b < 5960) {                // w2 -> B2t: 14 x 28
        int r = b - 5568;
        transpose_tile64(w2, B2t, 800, 800, 896, smem, r % 14, r / 14);
    } else if (b < 6156) {                // we -> BEt: 7 x 28
        int r = b - 5960;
        transpose_tile64(we, BEt, 800, 400, 896, smem, r % 7, r / 7);
    } else if (b < 6668) {                // build_A: one block per spectrum
        const int spec = b - 6156;
        const int t = threadIdx.x;
#pragma unroll
        for (int i = 0; i < 5; ++i)
            *(float4*)&smem[(i * 512 + t) * 4] = float4{0.f, 0.f, 0.f, 0.f};
        __syncthreads();
        {
            float m = mz[(size_t)spec * 512 + t];
            float v = inten[(size_t)spec * 512 + t];
            bool mask = (m >= 0.0f) && (m < 1000.0f);
            int idx = (int)(m / 0.01f);       // IEEE div + trunc, matches astype(int32)
            idx = min(max(idx, 0), 99999);
            if (mask && idx < 99990) {
                int g = idx / 30;
                float val = sqrtf(v);         // inten ** 0.5
                const float* w = bw + (size_t)idx * 3;
                atomicAdd(&smem[g * 3 + 0], val * w[0]);
                atomicAdd(&smem[g * 3 + 1], val * w[1]);
                atomicAdd(&smem[g * 3 + 2], val * w[2]);
            }
        }
        __syncthreads();
        bf16* Arow = A + (size_t)spec * K0A;
#pragma unroll
        for (int i = 0; i < 5; ++i) {
            int c = (i * 512 + t) * 4;
            float4 s = *(const float4*)&smem[c];
            bf16 o[4];
            o[0] = (bf16)((c + 0 < BOUT) ? bb[c + 0] + s.x : 0.f);
            o[1] = (bf16)((c + 1 < BOUT) ? bb[c + 1] + s.y : 0.f);
            o[2] = (bf16)((c + 2 < BOUT) ? bb[c + 2] + s.z : 0.f);
            o[3] = (bf16)((c + 3 < BOUT) ? bb[c + 3] + s.w : 0.f);
            *(ushort4*)&Arow[c] = *(ushort4*)o;
        }
    } else {                              // zero cosine accumulators
        for (int i = threadIdx.x; i < 768; i += 512) psums[i] = 0.f;
    }
}

// ---------------- GEMM0: 64x64xBK128, split-K=8 XCD-pinned, dbuf, slab stores (no atomics) ----------------
__global__ __launch_bounds__(256) void gemm0_splitk(const bf16* __restrict__ A,
                                                    const bf16* __restrict__ Bt,
                                                    float* __restrict__ Cslab) {
    constexpr int K0 = K0A, KITERS = 10, BK = 128;
    __shared__ __align__(16) bf16 As[2][64 * BK];   // 16 KB each
    __shared__ __align__(16) bf16 Bs[2][64 * BK];
    const int bid = blockIdx.x;
    const int kp = bid & 7;                   // kp == XCD (round-robin dispatch)
    const int tile = bid >> 3;                // 0..127
    const int mt = tile & 7, nt = tile >> 3;  // 8 x 16
    const int tid = threadIdx.x, wave = tid >> 6, lane = tid & 63;
    const int wm = wave & 1, wn = wave >> 1;
    const int lrow = lane & 15, quad = lane >> 4;
    const int l4 = lane >> 4, lc = (lane & 15) * 8;   // 4 rows / wave-call

    const bf16* Ag = A  + (size_t)(mt * 64) * K0 + kp * KITERS * BK;
    const bf16* Bg = Bt + (size_t)(nt * 64) * K0 + kp * KITERS * BK;

    auto stage = [&](int buf, int kk) {
        const int k = kk * BK;
#pragma unroll
        for (int j = 0; j < 4; ++j) {
            int row = j * 16 + wave * 4;
            gload_lds16(Ag + (size_t)(row + l4) * K0 + k + lc, &As[buf][row * BK]);
            gload_lds16(Bg + (size_t)(row + l4) * K0 + k + lc, &Bs[buf][row * BK]);
        }
    };

    f32x4 acc[2][2] = {};
    stage(0, 0);
    for (int kk = 0; kk < KITERS; ++kk) {
        const int cur = kk & 1;
        __syncthreads();                      // buf[cur] drained (vmcnt0 at barrier)
        if (kk + 1 < KITERS) stage(cur ^ 1, kk + 1);  // prefetch overlaps compute
#pragma unroll
        for (int ks = 0; ks < 4; ++ks) {
            bf16x8 af[2], bfr[2];
#pragma unroll
            for (int im = 0; im < 2; ++im)
                af[im] = *(const bf16x8*)&As[cur][(wm * 32 + im * 16 + lrow) * BK + ks * 32 + quad * 8];
#pragma unroll
            for (int in = 0; in < 2; ++in)
                bfr[in] = *(const bf16x8*)&Bs[cur][(wn * 32 + in * 16 + lrow) * BK + ks * 32 + quad * 8];
#pragma unroll
            for (int im = 0; im < 2; ++im)
#pragma unroll
                for (int in = 0; in < 2; ++in)
                    acc[im][in] = __builtin_amdgcn_mfma_f32_16x16x32_bf16(af[im], bfr[in], acc[im][in], 0, 0, 0);
        }
    }
    // plain stores into this kp's slab — no atomics, no fences
    float* C = Cslab + (size_t)kp * (NSPEC * N00);
#pragma unroll
    for (int im = 0; im < 2; ++im) {
        int row0 = mt * 64 + wm * 32 + im * 16 + quad * 4;
#pragma unroll
        for (int in = 0; in < 2; ++in) {
            int col = nt * 64 + wn * 32 + in * 16 + lrow;
#pragma unroll
            for (int r = 0; r < 4; ++r)
                C[(size_t)(row0 + r) * N00 + col] = acc[im][in][r];
        }
    }
}

// ---------------- reduce 8 slabs + bias + relu + bf16 cvt ----------------
__global__ __launch_bounds__(256) void reduce_bias_relu(const float* __restrict__ Cslab,
                                                        const float* __restrict__ b0,
                                                        bf16* __restrict__ H0b) {
    int idx = blockIdx.x * 256 + threadIdx.x;     // 131072 float4 chunks
    int r = idx >> 8, c = (idx & 255) * 4;
    float4 s = {0.f, 0.f, 0.f, 0.f};
#pragma unroll
    for (int kp = 0; kp < 8; ++kp) {
        float4 v = *(const float4*)&Cslab[(size_t)kp * (NSPEC * N00) + (size_t)r * N00 + c];
        s.x += v.x; s.y += v.y; s.z += v.z; s.w += v.w;
    }
    bf16 o[4];
    o[0] = (bf16)fmaxf(s.x + ((c + 0 < 1000) ? b0[c + 0] : 0.f), 0.f);
    o[1] = (bf16)fmaxf(s.y + ((c + 1 < 1000) ? b0[c + 1] : 0.f), 0.f);
    o[2] = (bf16)fmaxf(s.z + ((c + 2 < 1000) ? b0[c + 2] : 0.f), 0.f);
    o[3] = (bf16)fmaxf(s.w + ((c + 3 < 1000) ? b0[c + 3] : 0.f), 0.f);
    *(ushort4*)&H0b[(size_t)r * N00 + c] = *(ushort4*)o;
}

// ---------------- small GEMM: 32x32 tiles, BK=128, dbuf, fused bias+relu, bf16 out ----------------
__global__ __launch_bounds__(256) void gemm_small(const bf16* __restrict__ A,
                                                  const bf16* __restrict__ Bt,
                                                  const float* __restrict__ bias,
                                                  bf16* __restrict__ Ob,
                                                  int K0, int N0, int Nreal,
                                                  int kiters, int ntiles) {
    __shared__ __align__(16) bf16 As[2][32 * 128];
    __shared__ __align__(16) bf16 Bs[2][32 * 128];
    const int bid = blockIdx.x;
    const int mt = bid / ntiles, nt = bid % ntiles;
    const int tid = threadIdx.x, wave = tid >> 6, lane = tid & 63;
    const int wm = wave & 1, wn = wave >> 1;
    const int lrow = lane & 15, quad = lane >> 4;
    const int l4 = lane >> 4, lc = (lane & 15) * 8;

    const bf16* Ag = A  + (size_t)(mt * 32) * K0;
    const bf16* Bg = Bt + (size_t)(nt * 32) * K0;

    auto stage = [&](int buf, int kk) {
        const int k = kk * 128;
#pragma unroll
        for (int j = wave; j < 8; j += 4) {
            int row = j * 4;
            gload_lds16(Ag + (size_t)(row + l4) * K0 + k + lc, &As[buf][row * 128]);
            gload_lds16(Bg + (size_t)(row + l4) * K0 + k + lc, &Bs[buf][row * 128]);
        }
    };

    f32x4 acc = {};
    stage(0, 0);
    for (int kk = 0; kk < kiters; ++kk) {
        const int cur = kk & 1;
        __syncthreads();
        if (kk + 1 < kiters) stage(cur ^ 1, kk + 1);
#pragma unroll
        for (int ks = 0; ks < 4; ++ks) {
            bf16x8 af  = *(const bf16x8*)&As[cur][(wm * 16 + lrow) * 128 + ks * 32 + quad * 8];
            bf16x8 bfr = *(const bf16x8*)&Bs[cur][(wn * 16 + lrow) * 128 + ks * 32 + quad * 8];
            acc = __builtin_amdgcn_mfma_f32_16x16x32_bf16(af, bfr, acc, 0, 0, 0);
        }
    }
    int row0 = mt * 32 + wm * 16 + quad * 4;
    int col  = nt * 32 + wn * 16 + lrow;
    float bv = (col < Nreal) ? bias[col] : 0.f;
#pragma unroll
    for (int r = 0; r < 4; ++r) {
        float v = fmaxf(acc[r] + bv, 0.f);
        Ob[(size_t)(row0 + r) * N0 + col] = (bf16)v;
    }
}

// ---------------- last GEMM + cosine partials (atomic psums, NO fences/completion) ----------------
__global__ __launch_bounds__(256) void gemm_last(const bf16* __restrict__ A,
                                                 const bf16* __restrict__ Bt,
                                                 const float* __restrict__ bias,
                                                 float* __restrict__ psums,
                                                 int K0, int kiters, int ntiles) {
    __shared__ __align__(16) bf16 As[2][32 * 128];
    __shared__ __align__(16) bf16 Bs[2][32 * 128];
    const int bid = blockIdx.x;
    const int mt = bid / ntiles, nt = bid % ntiles;
    const int tid = threadIdx.x, wave = tid >> 6, lane = tid & 63;
    const int wm = wave & 1, wn = wave >> 1;
    const int lrow = lane & 15, quad = lane >> 4;
    const int l4 = lane >> 4, lc = (lane & 15) * 8;

    const bf16* Ag = A  + (size_t)(mt * 32) * K0;
    const bf16* Bg = Bt + (size_t)(nt * 32) * K0;

    auto stage = [&](int buf, int kk) {
        const int k = kk * 128;
#pragma unroll
        for (int j = wave; j < 8; j += 4) {
            int row = j * 4;
            gload_lds16(Ag + (size_t)(row + l4) * K0 + k + lc, &As[buf][row * 128]);
            gload_lds16(Bg + (size_t)(row + l4) * K0 + k + lc, &Bs[buf][row * 128]);
        }
    };

    f32x4 acc = {};
    stage(0, 0);
    for (int kk = 0; kk < kiters; ++kk) {
        const int cur = kk & 1;
        __syncthreads();
        if (kk + 1 < kiters) stage(cur ^ 1, kk + 1);
#pragma unroll
        for (int ks = 0; ks < 4; ++ks) {
            bf16x8 af  = *(const bf16x8*)&As[cur][(wm * 16 + lrow) * 128 + ks * 32 + quad * 8];
            bf16x8 bfr = *(const bf16x8*)&Bs[cur][(wn * 16 + lrow) * 128 + ks * 32 + quad * 8];
            acc = __builtin_amdgcn_mfma_f32_16x16x32_bf16(af, bfr, acc, 0, 0, 0);
        }
    }
    // cosine partials: rows rowbase..rowbase+3 (rowbase even), col = this lane's col
    int rowbase = mt * 32 + wm * 16 + quad * 4;
    int col     = nt * 32 + wn * 16 + lrow;
    bool valid  = (col < 400);
    float bv = valid ? bias[col] : 0.f;
    float v[4];
#pragma unroll
    for (int r = 0; r < 4; ++r) v[r] = valid ? (acc[r] + bv) : 0.f;
    int p0 = rowbase >> 1;                    // pairs p0, p0+1
    float sums[6] = {v[0] * v[1], v[0] * v[0], v[1] * v[1],
                     v[2] * v[3], v[2] * v[2], v[3] * v[3]};
#pragma unroll
    for (int off = 1; off < 16; off <<= 1)
#pragma unroll
        for (int s = 0; s < 6; ++s) sums[s] += __shfl_xor(sums[s], off);
    if (lrow == 0) {
#pragma unroll
        for (int s = 0; s < 3; ++s) {
            atomicAdd(&psums[(p0 + 0) * 3 + s], sums[s]);
            atomicAdd(&psums[(p0 + 1) * 3 + s], sums[3 + s]);
        }
    }
}

// ---------------- finalize cosine from psums ----------------
__global__ __launch_bounds__(256) void cosine_fin(const float* __restrict__ psums,
                                                  float* __restrict__ out) {
    int t = threadIdx.x;
    float d  = psums[t * 3 + 0];
    float s1 = psums[t * 3 + 1];
    float s2 = psums[t * 3 + 2];
    float n1 = fmaxf(sqrtf(s1), 1e-6f);
    float n2 = fmaxf(sqrtf(s2), 1e-6f);
    out[t] = d / (n1 * n2);
}

extern "C" void kernel_launch(void* const* d_in, const int* in_sizes, int n_in,
                              void* d_out, int out_size, void* d_ws, size_t ws_size,
                              hipStream_t stream) {
    const float* mz    = (const float*)d_in[0];
    const float* inten = (const float*)d_in[1];
    const float* bw    = (const float*)d_in[2];
    const float* bb    = (const float*)d_in[3];
    const float* w0    = (const float*)d_in[4];
    const float* b0    = (const float*)d_in[5];
    const float* w1    = (const float*)d_in[6];
    const float* b1    = (const float*)d_in[7];
    const float* w2    = (const float*)d_in[8];
    const float* b2    = (const float*)d_in[9];
    const float* we    = (const float*)d_in[10];
    const float* be    = (const float*)d_in[11];
    float* out = (float*)d_out;

    char* ws = (char*)d_ws;
    size_t off = 0;
    auto alloc = [&](size_t bytes) { char* p = ws + off; off += (bytes + 255) & ~(size_t)255; return p; };
    bf16*  A     = (bf16*) alloc((size_t)NSPEC * K0A * 2);
    bf16*  B0t   = (bf16*) alloc((size_t)N00 * K0A * 2);
    bf16*  B1t   = (bf16*) alloc((size_t)N01 * 1024 * 2);
    bf16*  B2t   = (bf16*) alloc((size_t)N02 * 896 * 2);
    bf16*  BEt   = (bf16*) alloc((size_t)N03 * 896 * 2);
    float* Cslab = (float*)alloc((size_t)8 * NSPEC * N00 * 4);   // 16 MB
    bf16*  H0b   = (bf16*) alloc((size_t)NSPEC * N00 * 2);
    bf16*  H1b   = (bf16*) alloc((size_t)NSPEC * N01 * 2);
    bf16*  H2b   = (bf16*) alloc((size_t)NSPEC * N02 * 2);
    float* psums = (float*)alloc(768 * 4);

    // 1: weight transposes + build_A + zero psums (one kernel)
    prep_all<<<6669, 512, 0, stream>>>(mz, inten, bw, bb, w0, w1, w2, we,
                                       A, B0t, B1t, B2t, BEt, psums);
    // 2: big GEMM, split-K=8 XCD-pinned, BK=128, slab stores
    gemm0_splitk<<<1024, 256, 0, stream>>>(A, B0t, Cslab);
    // 3: slab reduce + bias + relu + bf16 cvt
    reduce_bias_relu<<<512, 256, 0, stream>>>(Cslab, b0, H0b);
    // 4-5: small fused GEMMs (bias+relu+bf16)
    gemm_small<<<448, 256, 0, stream>>>(H0b, B1t, b1, H1b, 1024, N01, 800, 8, 28);
    gemm_small<<<448, 256, 0, stream>>>(H1b, B2t, b2, H2b, 896,  N02, 800, 7, 28);
    // 6: last GEMM + cosine partials (plain atomics, no fences)
    gemm_last<<<224, 256, 0, stream>>>(H2b, BEt, be, psums, 896, 7, 14);
    // 7: finalize
    cosine_fin<<<1, 256, 0, stream>>>(psums, out);
}

// Round 7
// 167.474 us; speedup vs baseline: 1.1900x; 1.1900x over previous
//
#include <hip/hip_runtime.h>

typedef __bf16 bf16;
typedef __bf16 bf16x8 __attribute__((ext_vector_type(8)));
typedef float  f32x4  __attribute__((ext_vector_type(4)));

// Problem constants
#define NSPEC   512          // 256 pairs * 2
#define BOUT    9999         // GROUPS*3
#define K0A     10240        // BOUT padded to 8*20*64 (ksplit*kiters*BK)
#define N00     1024         // 1000 padded
#define N01     896          // 800 padded
#define N02     896
#define N03     448          // 400 padded (14*32)

// async global->LDS, 16B per lane; lds base must be wave-uniform (HW adds lane*16)
__device__ __forceinline__ void gload_lds16(const bf16* g, bf16* l) {
    auto* gp = reinterpret_cast<const __attribute__((address_space(1))) unsigned int*>(
        reinterpret_cast<uintptr_t>(g));
    auto* lp = reinterpret_cast<__attribute__((address_space(3))) unsigned int*>(
        reinterpret_cast<uintptr_t>(l));
    __builtin_amdgcn_global_load_lds(gp, lp, 16, 0, 0);
}

// ---------------- transpose helper: 64(n) x 32(k) tile, 512 threads ----------------
__device__ __forceinline__ void transpose_tile64(const float* __restrict__ src,
                                                 bf16* __restrict__ dst,
                                                 int K, int N, int K0,
                                                 float* tile, int bx, int by) {
    int n0 = bx * 64, k0 = by * 32;
    int t = threadIdx.x;
    {
        int kr = t >> 4, nc = (t & 15) * 4;          // 32 rows x 64 cols
        int gk = k0 + kr;
#pragma unroll
        for (int e = 0; e < 4; ++e) {
            int gn = n0 + nc + e;
            tile[kr * 65 + nc + e] = (gk < K && gn < N) ? src[(size_t)gk * N + gn] : 0.0f;
        }
    }
    __syncthreads();
    {
        int nr = t >> 3, kc = (t & 7) * 4;           // 64 n-rows x 32 k-cols
        bf16 v[4];
#pragma unroll
        for (int e = 0; e < 4; ++e) v[e] = (bf16)tile[(kc + e) * 65 + nr];
        *(ushort4*)&dst[(size_t)(n0 + nr) * K0 + k0 + kc] = *(ushort4*)v;
    }
}

// ---------------- mega-prep: weight transposes + build_A + zero psums ----------------
__global__ __launch_bounds__(512) void prep_all(const float* __restrict__ mz,
                                                const float* __restrict__ inten,
                                                const float* __restrict__ bw,
                                                const float* __restrict__ bb,
                                                const float* __restrict__ w0,
                                                const float* __restrict__ w1,
                                                const float* __restrict__ w2,
                                                const float* __restrict__ we,
                                                bf16* __restrict__ A,
                                                bf16* __restrict__ B0t,
                                                bf16* __restrict__ B1t,
                                                bf16* __restrict__ B2t,
                                                bf16* __restrict__ BEt,
                                                float* __restrict__ psums) {
    __shared__ float smem[K0A];    // 40 KB: sacc for build_A, tile[32*65] for transposes
    int b = blockIdx.x;
    if (b < 5120) {                       // w0 -> B0t: 16 n-tiles x 320 k-tiles
        transpose_tile64(w0, B0t, BOUT, 1000, K0A, smem, b & 15, b >> 4);
    } else if (b < 5568) {                // w1 -> B1t: 14 x 32
        int r = b - 5120;
        transpose_tile64(w1, B1t, 1000, 800, 1024, smem, r % 14, r / 14);
    } else if (b < 5960) {                // w2 -> B2t: 14 x 28
        int r = b - 5568;
        transpose_tile64(w2, B2t, 800, 800, 896, smem, r % 14, r / 14);
    } else if (b < 6156) {                // we -> BEt: 7 x 28
        int r = b - 5960;
        transpose_tile64(we, BEt, 800, 400, 896, smem, r % 7, r / 7);
    } else if (b < 6668) {                // build_A: one block per spectrum
        const int spec = b - 6156;
        const int t = threadIdx.x;
#pragma unroll
        for (int i = 0; i < 5; ++i)
            *(float4*)&smem[(i * 512 + t) * 4] = float4{0.f, 0.f, 0.f, 0.f};
        __syncthreads();
        {
            float m = mz[(size_t)spec * 512 + t];
            float v = inten[(size_t)spec * 512 + t];
            bool mask = (m >= 0.0f) && (m < 1000.0f);
            int idx = (int)(m / 0.01f);       // IEEE div + trunc, matches astype(int32)
            idx = min(max(idx, 0), 99999);
            if (mask && idx < 99990) {
                int g = idx / 30;
                float val = sqrtf(v);         // inten ** 0.5
                const float* w = bw + (size_t)idx * 3;
                atomicAdd(&smem[g * 3 + 0], val * w[0]);
                atomicAdd(&smem[g * 3 + 1], val * w[1]);
                atomicAdd(&smem[g * 3 + 2], val * w[2]);
            }
        }
        __syncthreads();
        bf16* Arow = A + (size_t)spec * K0A;
#pragma unroll
        for (int i = 0; i < 5; ++i) {
            int c = (i * 512 + t) * 4;
            float4 s = *(const float4*)&smem[c];
            bf16 o[4];
            o[0] = (bf16)((c + 0 < BOUT) ? bb[c + 0] + s.x : 0.f);
            o[1] = (bf16)((c + 1 < BOUT) ? bb[c + 1] + s.y : 0.f);
            o[2] = (bf16)((c + 2 < BOUT) ? bb[c + 2] + s.z : 0.f);
            o[3] = (bf16)((c + 3 < BOUT) ? bb[c + 3] + s.w : 0.f);
            *(ushort4*)&Arow[c] = *(ushort4*)o;
        }
    } else {                              // zero cosine accumulators
        for (int i = threadIdx.x; i < 768; i += 512) psums[i] = 0.f;
    }
}

// ---------------- GEMM0: 64x64xBK64, split-K=8 XCD-pinned, dbuf, XOR-swizzled LDS, slab stores ----------------
// Swizzle: chunk c (16B) of row r stored at physical chunk c ^ (r & 7).
// Staging picks the matching global chunk per lane (coalesced within each 128B row);
// fragment reads land on 16 distinct chunks per quad -> <=2-way bank aliasing (free, m136).
__global__ __launch_bounds__(256) void gemm0_splitk(const bf16* __restrict__ A,
                                                    const bf16* __restrict__ Bt,
                                                    float* __restrict__ Cslab) {
    constexpr int K0 = K0A, KITERS = 20, BK = 64;
    __shared__ __align__(16) bf16 As[2][64 * BK];   // 8 KB each buf
    __shared__ __align__(16) bf16 Bs[2][64 * BK];
    const int bid = blockIdx.x;
    const int kp = bid & 7;                   // kp == XCD (round-robin dispatch)
    const int tile = bid >> 3;                // 0..127
    const int mt = tile & 7, nt = tile >> 3;  // 8 x 16
    const int tid = threadIdx.x, wave = tid >> 6, lane = tid & 63;
    const int wm = wave & 1, wn = wave >> 1;
    const int lrow = lane & 15, quad = lane >> 4;

    const bf16* Ag = A  + (size_t)(mt * 64) * K0 + kp * KITERS * BK;
    const bf16* Bg = Bt + (size_t)(nt * 64) * K0 + kp * KITERS * BK;

    auto stage = [&](int buf, int kk) {
        const int k = kk * BK;
#pragma unroll
        for (int j = 0; j < 2; ++j) {
            int row0 = j * 32 + wave * 8;              // wave-uniform base row
            int row = row0 + (lane >> 3);              // this lane's row
            int ch  = (lane & 7) ^ (row & 7);          // swizzled source chunk
            gload_lds16(Ag + (size_t)row * K0 + k + ch * 8, &As[buf][row0 * BK]);
            gload_lds16(Bg + (size_t)row * K0 + k + ch * 8, &Bs[buf][row0 * BK]);
        }
    };

    f32x4 acc[2][2] = {};
    stage(0, 0);
    for (int kk = 0; kk < KITERS; ++kk) {
        const int cur = kk & 1;
        __syncthreads();                      // buf[cur] drained (vmcnt0 at barrier)
        if (kk + 1 < KITERS) stage(cur ^ 1, kk + 1);  // prefetch overlaps compute
#pragma unroll
        for (int ks = 0; ks < 2; ++ks) {
            bf16x8 af[2], bfr[2];
#pragma unroll
            for (int im = 0; im < 2; ++im) {
                int r = wm * 32 + im * 16 + lrow;
                int c = ks * 4 + quad;
                af[im] = *(const bf16x8*)&As[cur][r * BK + ((c ^ (r & 7)) << 3)];
            }
#pragma unroll
            for (int in = 0; in < 2; ++in) {
                int r = wn * 32 + in * 16 + lrow;
                int c = ks * 4 + quad;
                bfr[in] = *(const bf16x8*)&Bs[cur][r * BK + ((c ^ (r & 7)) << 3)];
            }
#pragma unroll
            for (int im = 0; im < 2; ++im)
#pragma unroll
                for (int in = 0; in < 2; ++in)
                    acc[im][in] = __builtin_amdgcn_mfma_f32_16x16x32_bf16(af[im], bfr[in], acc[im][in], 0, 0, 0);
        }
    }
    // plain stores into this kp's slab — no atomics, no fences
    float* C = Cslab + (size_t)kp * (NSPEC * N00);
#pragma unroll
    for (int im = 0; im < 2; ++im) {
        int row0 = mt * 64 + wm * 32 + im * 16 + quad * 4;
#pragma unroll
        for (int in = 0; in < 2; ++in) {
            int col = nt * 64 + wn * 32 + in * 16 + lrow;
#pragma unroll
            for (int r = 0; r < 4; ++r)
                C[(size_t)(row0 + r) * N00 + col] = acc[im][in][r];
        }
    }
}

// ---------------- reduce 8 slabs + bias + relu + bf16 cvt ----------------
__global__ __launch_bounds__(256) void reduce_bias_relu(const float* __restrict__ Cslab,
                                                        const float* __restrict__ b0,
                                                        bf16* __restrict__ H0b) {
    int idx = blockIdx.x * 256 + threadIdx.x;     // 131072 float4 chunks
    int r = idx >> 8, c = (idx & 255) * 4;
    float4 s = {0.f, 0.f, 0.f, 0.f};
#pragma unroll
    for (int kp = 0; kp < 8; ++kp) {
        float4 v = *(const float4*)&Cslab[(size_t)kp * (NSPEC * N00) + (size_t)r * N00 + c];
        s.x += v.x; s.y += v.y; s.z += v.z; s.w += v.w;
    }
    bf16 o[4];
    o[0] = (bf16)fmaxf(s.x + ((c + 0 < 1000) ? b0[c + 0] : 0.f), 0.f);
    o[1] = (bf16)fmaxf(s.y + ((c + 1 < 1000) ? b0[c + 1] : 0.f), 0.f);
    o[2] = (bf16)fmaxf(s.z + ((c + 2 < 1000) ? b0[c + 2] : 0.f), 0.f);
    o[3] = (bf16)fmaxf(s.w + ((c + 3 < 1000) ? b0[c + 3] : 0.f), 0.f);
    *(ushort4*)&H0b[(size_t)r * N00 + c] = *(ushort4*)o;
}

// ---------------- small GEMM: 32x32 tiles, BK=128, dbuf, XOR swizzle, fused bias+relu ----------------
__global__ __launch_bounds__(256) void gemm_small(const bf16* __restrict__ A,
                                                  const bf16* __restrict__ Bt,
                                                  const float* __restrict__ bias,
                                                  bf16* __restrict__ Ob,
                                                  int K0, int N0, int Nreal,
                                                  int kiters, int ntiles) {
    __shared__ __align__(16) bf16 As[2][32 * 128];
    __shared__ __align__(16) bf16 Bs[2][32 * 128];
    const int bid = blockIdx.x;
    const int mt = bid / ntiles, nt = bid % ntiles;
    const int tid = threadIdx.x, wave = tid >> 6, lane = tid & 63;
    const int wm = wave & 1, wn = wave >> 1;
    const int lrow = lane & 15, quad = lane >> 4;

    const bf16* Ag = A  + (size_t)(mt * 32) * K0;
    const bf16* Bg = Bt + (size_t)(nt * 32) * K0;

    auto stage = [&](int buf, int kk) {
        const int k = kk * 128;
#pragma unroll
        for (int j = wave; j < 8; j += 4) {           // j in {wave, wave+4}
            int row0 = j * 4;
            int row = row0 + (lane >> 4);
            int ch  = (lane & 15) ^ (row & 15);       // swizzled source chunk (16 chunks/row)
            gload_lds16(Ag + (size_t)row * K0 + k + ch * 8, &As[buf][row0 * 128]);
            gload_lds16(Bg + (size_t)row * K0 + k + ch * 8, &Bs[buf][row0 * 128]);
        }
    };

    f32x4 acc = {};
    stage(0, 0);
    for (int kk = 0; kk < kiters; ++kk) {
        const int cur = kk & 1;
        __syncthreads();
        if (kk + 1 < kiters) stage(cur ^ 1, kk + 1);
#pragma unroll
        for (int ks = 0; ks < 4; ++ks) {
            int ra = wm * 16 + lrow, rb = wn * 16 + lrow;
            int c = ks * 4 + quad;
            bf16x8 af  = *(const bf16x8*)&As[cur][ra * 128 + ((c ^ (ra & 15)) << 3)];
            bf16x8 bfr = *(const bf16x8*)&Bs[cur][rb * 128 + ((c ^ (rb & 15)) << 3)];
            acc = __builtin_amdgcn_mfma_f32_16x16x32_bf16(af, bfr, acc, 0, 0, 0);
        }
    }
    int row0 = mt * 32 + wm * 16 + quad * 4;
    int col  = nt * 32 + wn * 16 + lrow;
    float bv = (col < Nreal) ? bias[col] : 0.f;
#pragma unroll
    for (int r = 0; r < 4; ++r) {
        float v = fmaxf(acc[r] + bv, 0.f);
        Ob[(size_t)(row0 + r) * N0 + col] = (bf16)v;
    }
}

// ---------------- last GEMM + cosine partials (atomic psums, NO fences/completion) ----------------
__global__ __launch_bounds__(256) void gemm_last(const bf16* __restrict__ A,
                                                 const bf16* __restrict__ Bt,
                                                 const float* __restrict__ bias,
                                                 float* __restrict__ psums,
                                                 int K0, int kiters, int ntiles) {
    __shared__ __align__(16) bf16 As[2][32 * 128];
    __shared__ __align__(16) bf16 Bs[2][32 * 128];
    const int bid = blockIdx.x;
    const int mt = bid / ntiles, nt = bid % ntiles;
    const int tid = threadIdx.x, wave = tid >> 6, lane = tid & 63;
    const int wm = wave & 1, wn = wave >> 1;
    const int lrow = lane & 15, quad = lane >> 4;

    const bf16* Ag = A  + (size_t)(mt * 32) * K0;
    const bf16* Bg = Bt + (size_t)(nt * 32) * K0;

    auto stage = [&](int buf, int kk) {
        const int k = kk * 128;
#pragma unroll
        for (int j = wave; j < 8; j += 4) {
            int row0 = j * 4;
            int row = row0 + (lane >> 4);
            int ch  = (lane & 15) ^ (row & 15);
            gload_lds16(Ag + (size_t)row * K0 + k + ch * 8, &As[buf][row0 * 128]);
            gload_lds16(Bg + (size_t)row * K0 + k + ch * 8, &Bs[buf][row0 * 128]);
        }
    };

    f32x4 acc = {};
    stage(0, 0);
    for (int kk = 0; kk < kiters; ++kk) {
        const int cur = kk & 1;
        __syncthreads();
        if (kk + 1 < kiters) stage(cur ^ 1, kk + 1);
#pragma unroll
        for (int ks = 0; ks < 4; ++ks) {
            int ra = wm * 16 + lrow, rb = wn * 16 + lrow;
            int c = ks * 4 + quad;
            bf16x8 af  = *(const bf16x8*)&As[cur][ra * 128 + ((c ^ (ra & 15)) << 3)];
            bf16x8 bfr = *(const bf16x8*)&Bs[cur][rb * 128 + ((c ^ (rb & 15)) << 3)];
            acc = __builtin_amdgcn_mfma_f32_16x16x32_bf16(af, bfr, acc, 0, 0, 0);
        }
    }
    // cosine partials: rows rowbase..rowbase+3 (rowbase even), col = this lane's col
    int rowbase = mt * 32 + wm * 16 + quad * 4;
    int col     = nt * 32 + wn * 16 + lrow;
    bool valid  = (col < 400);
    float bv = valid ? bias[col] : 0.f;
    float v[4];
#pragma unroll
    for (int r = 0; r < 4; ++r) v[r] = valid ? (acc[r] + bv) : 0.f;
    int p0 = rowbase >> 1;                    // pairs p0, p0+1
    float sums[6] = {v[0] * v[1], v[0] * v[0], v[1] * v[1],
                     v[2] * v[3], v[2] * v[2], v[3] * v[3]};
#pragma unroll
    for (int off = 1; off < 16; off <<= 1)
#pragma unroll
        for (int s = 0; s < 6; ++s) sums[s] += __shfl_xor(sums[s], off);
    if (lrow == 0) {
#pragma unroll
        for (int s = 0; s < 3; ++s) {
            atomicAdd(&psums[(p0 + 0) * 3 + s], sums[s]);
            atomicAdd(&psums[(p0 + 1) * 3 + s], sums[3 + s]);
        }
    }
}

// ---------------- finalize cosine from psums ----------------
__global__ __launch_bounds__(256) void cosine_fin(const float* __restrict__ psums,
                                                  float* __restrict__ out) {
    int t = threadIdx.x;
    float d  = psums[t * 3 + 0];
    float s1 = psums[t * 3 + 1];
    float s2 = psums[t * 3 + 2];
    float n1 = fmaxf(sqrtf(s1), 1e-6f);
    float n2 = fmaxf(sqrtf(s2), 1e-6f);
    out[t] = d / (n1 * n2);
}

extern "C" void kernel_launch(void* const* d_in, const int* in_sizes, int n_in,
                              void* d_out, int out_size, void* d_ws, size_t ws_size,
                              hipStream_t stream) {
    const float* mz    = (const float*)d_in[0];
    const float* inten = (const float*)d_in[1];
    const float* bw    = (const float*)d_in[2];
    const float* bb    = (const float*)d_in[3];
    const float* w0    = (const float*)d_in[4];
    const float* b0    = (const float*)d_in[5];
    const float* w1    = (const float*)d_in[6];
    const float* b1    = (const float*)d_in[7];
    const float* w2    = (const float*)d_in[8];
    const float* b2    = (const float*)d_in[9];
    const float* we    = (const float*)d_in[10];
    const float* be    = (const float*)d_in[11];
    float* out = (float*)d_out;

    char* ws = (char*)d_ws;
    size_t off = 0;
    auto alloc = [&](size_t bytes) { char* p = ws + off; off += (bytes + 255) & ~(size_t)255; return p; };
    bf16*  A     = (bf16*) alloc((size_t)NSPEC * K0A * 2);
    bf16*  B0t   = (bf16*) alloc((size_t)N00 * K0A * 2);
    bf16*  B1t   = (bf16*) alloc((size_t)N01 * 1024 * 2);
    bf16*  B2t   = (bf16*) alloc((size_t)N02 * 896 * 2);
    bf16*  BEt   = (bf16*) alloc((size_t)N03 * 896 * 2);
    float* Cslab = (float*)alloc((size_t)8 * NSPEC * N00 * 4);   // 16 MB
    bf16*  H0b   = (bf16*) alloc((size_t)NSPEC * N00 * 2);
    bf16*  H1b   = (bf16*) alloc((size_t)NSPEC * N01 * 2);
    bf16*  H2b   = (bf16*) alloc((size_t)NSPEC * N02 * 2);
    float* psums = (float*)alloc(768 * 4);

    // 1: weight transposes + build_A + zero psums (one kernel)
    prep_all<<<6669, 512, 0, stream>>>(mz, inten, bw, bb, w0, w1, w2, we,
                                       A, B0t, B1t, B2t, BEt, psums);
    // 2: big GEMM, split-K=8 XCD-pinned, BK=64, swizzled LDS, slab stores
    gemm0_splitk<<<1024, 256, 0, stream>>>(A, B0t, Cslab);
    // 3: slab reduce + bias + relu + bf16 cvt
    reduce_bias_relu<<<512, 256, 0, stream>>>(Cslab, b0, H0b);
    // 4-5: small fused GEMMs (bias+relu+bf16)
    gemm_small<<<448, 256, 0, stream>>>(H0b, B1t, b1, H1b, 1024, N01, 800, 8, 28);
    gemm_small<<<448, 256, 0, stream>>>(H1b, B2t, b2, H2b, 896,  N02, 800, 7, 28);
    // 6: last GEMM + cosine partials (plain atomics, no fences)
    gemm_last<<<224, 256, 0, stream>>>(H2b, BEt, be, psums, 896, 7, 14);
    // 7: finalize
    cosine_fin<<<1, 256, 0, stream>>>(psums, out);
}